// Round 2
// baseline (4372.639 us; speedup 1.0000x reference)
//
#include <hip/hip_runtime.h>
#include <hip/hip_bf16.h>
#include <hip/hip_cooperative_groups.h>

namespace cg = cooperative_groups;

typedef __attribute__((ext_vector_type(8))) short bf16x8;
typedef __attribute__((ext_vector_type(4))) float f32x4;

static constexpr int BB = 256;   // batch
static constexpr int TT = 33;    // time (input)
static constexpr int EE = 1024;  // embed
static constexpr int LL = 32;    // scan steps = T-1
static constexpr int NG = 4096;  // 4*E gate rows

__device__ __forceinline__ short f2bf(float f) {
  unsigned u = __builtin_bit_cast(unsigned, f);
  u += 0x7fffu + ((u >> 16) & 1u);   // RNE
  return (short)(u >> 16);
}

__device__ __forceinline__ bf16x8 cvt8(f32x4 a, f32x4 b) {
  bf16x8 r;
  r[0] = f2bf(a[0]); r[1] = f2bf(a[1]); r[2] = f2bf(a[2]); r[3] = f2bf(a[3]);
  r[4] = f2bf(b[0]); r[5] = f2bf(b[1]); r[6] = f2bf(b[2]); r[7] = f2bf(b[3]);
  return r;
}

__device__ __forceinline__ float sigm(float x) { return 1.0f / (1.0f + __expf(-x)); }
__device__ __forceinline__ float tanh_f(float x) { return 1.0f - 2.0f / (__expf(2.0f * x) + 1.0f); }

// ---- prep: x fp32 -> bf16 [t][row][e] for t<32; c0 = x[:,1,:]
__global__ __launch_bounds__(256) void lstm_prep(
    const float* __restrict__ x, short* __restrict__ xbf, float* __restrict__ c_io)
{
  int g = blockIdx.x * 256 + threadIdx.x;      // 1,048,576 threads, 8 elems each
  int eb  = g & 127;
  int row = (g >> 7) & 255;
  int t   = g >> 15;
  const float* src = x + ((size_t)row * TT + t) * EE + (eb << 3);
  f32x4 lo = *(const f32x4*)src;
  f32x4 hi = *(const f32x4*)(src + 4);
  *(bf16x8*)(xbf + ((size_t)t * BB + row) * EE + (eb << 3)) = cvt8(lo, hi);
  if (t == 1) {
    float* cd = c_io + (size_t)row * EE + (eb << 3);
    *(f32x4*)cd = lo;
    *(f32x4*)(cd + 4) = hi;
  }
}

// ---- gx: G_x[t] = x_t @ W_ih[t]^T for ALL t at once. Grid (256, 32) x 256 thr.
__global__ __launch_bounds__(256) void lstm_gx(
    const short* __restrict__ xbf,   // [32][256][1024] bf16
    const float* __restrict__ Wih,   // [32][4096][1024]
    float* __restrict__ Gx)          // [32][256][4096]
{
  const int t    = blockIdx.y;
  const int tid  = threadIdx.x;
  const int lane = tid & 63;
  const int wv   = tid >> 6;      // gate 0..3
  const int lr   = lane & 15;
  const int kg   = lane >> 4;
  const int e0   = (blockIdx.x & 63) << 4;
  const int row0 = (blockIdx.x >> 6) << 6;

  f32x4 acc0{}, acc1{}, acc2{}, acc3{};

  const float* wp = Wih + (size_t)t * NG * EE + (size_t)(wv * EE + e0 + lr) * EE + (kg << 3);
  const short* a0 = xbf + ((size_t)t * BB + row0 +  0 + lr) * EE + (kg << 3);
  const short* a1 = a0 + 16 * EE;
  const short* a2 = a0 + 32 * EE;
  const short* a3 = a0 + 48 * EE;
#pragma unroll 4
  for (int kc = 0; kc < 32; ++kc) {
    bf16x8 bfr = cvt8(*(const f32x4*)wp, *(const f32x4*)(wp + 4));
    acc0 = __builtin_amdgcn_mfma_f32_16x16x32_bf16(*(const bf16x8*)a0, bfr, acc0, 0, 0, 0);
    acc1 = __builtin_amdgcn_mfma_f32_16x16x32_bf16(*(const bf16x8*)a1, bfr, acc1, 0, 0, 0);
    acc2 = __builtin_amdgcn_mfma_f32_16x16x32_bf16(*(const bf16x8*)a2, bfr, acc2, 0, 0, 0);
    acc3 = __builtin_amdgcn_mfma_f32_16x16x32_bf16(*(const bf16x8*)a3, bfr, acc3, 0, 0, 0);
    wp += 32; a0 += 32; a1 += 32; a2 += 32; a3 += 32;
  }

  // D layout: col = lane&15, row-in-tile = 4*kg + j. 16-lane groups store 64B runs.
  const f32x4 av[4] = {acc0, acc1, acc2, acc3};
#pragma unroll
  for (int m = 0; m < 4; ++m)
#pragma unroll
    for (int j = 0; j < 4; ++j)
      Gx[((size_t)t * BB + row0 + (m << 4) + (kg << 2) + j) * NG + wv * EE + e0 + lr] = av[m][j];
}

// ---- rec: cooperative, one launch, 32 steps with grid-wide sync.
// Grid 256 WGs x 512 thr. WG b: rows row0=(b>>6)*64, e-slice e0=(b&63)*16, all 4 gates.
// Wave wv: gate g=wv&3, row-half hf=wv>>2 (32 rows -> 2 MFMA row-tiles).
__global__ __launch_bounds__(512) void lstm_rec(
    const float* __restrict__ Gx,    // [32][256][4096]
    const float* __restrict__ Whh,   // [32][4096][1024]
    short* __restrict__ hbf,         // [256][1024] bf16
    float* __restrict__ c_io,        // [256][1024] fp32 (d_out c region)
    float* __restrict__ h_out)       // [256][1024] fp32 (d_out h region)
{
  cg::grid_group grid = cg::this_grid();
  __shared__ float lds_g[4][64][16];

  const int tid  = threadIdx.x;
  const int lane = tid & 63;
  const int wv   = tid >> 6;      // 0..7
  const int g    = wv & 3;
  const int hf   = wv >> 2;
  const int lr   = lane & 15;
  const int kg   = lane >> 4;
  const int e0   = (blockIdx.x & 63) << 4;
  const int row0 = (blockIdx.x >> 6) << 6;

  for (int t = 0; t < LL; ++t) {
    f32x4 acc0{}, acc1{};

    if (t > 0) {
      const float* wp  = Whh + (size_t)t * NG * EE + (size_t)(g * EE + e0 + lr) * EE + (kg << 3);
      const short* h0p = hbf + (size_t)(row0 + hf * 32 + lr) * EE + (kg << 3);
      const short* h1p = h0p + 16 * EE;
#pragma unroll 4
      for (int kc = 0; kc < 32; ++kc) {
        bf16x8 bfr = cvt8(*(const f32x4*)wp, *(const f32x4*)(wp + 4));
        acc0 = __builtin_amdgcn_mfma_f32_16x16x32_bf16(*(const bf16x8*)h0p, bfr, acc0, 0, 0, 0);
        acc1 = __builtin_amdgcn_mfma_f32_16x16x32_bf16(*(const bf16x8*)h1p, bfr, acc1, 0, 0, 0);
        wp += 32; h0p += 32; h1p += 32;
      }
    }

#pragma unroll
    for (int j = 0; j < 4; ++j) {
      lds_g[g][hf * 32 +      (kg << 2) + j][lr] = acc0[j];
      lds_g[g][hf * 32 + 16 + (kg << 2) + j][lr] = acc1[j];
    }
    __syncthreads();

#pragma unroll
    for (int q = 0; q < 2; ++q) {
      int idx = tid + (q << 9);          // 0..1023 = 64 rows x 16 cols
      int rl = idx >> 4, el = idx & 15;
      const float* gxp = Gx + ((size_t)t * BB + row0 + rl) * NG + e0 + el;
      float gi = lds_g[0][rl][el] + gxp[0];
      float gf = lds_g[1][rl][el] + gxp[EE];
      float gg = lds_g[2][rl][el] + gxp[2 * EE];
      float go = lds_g[3][rl][el] + gxp[3 * EE];
      size_t off = (size_t)(row0 + rl) * EE + (e0 + el);
      float c_old = c_io[off];
      float c_new = sigm(gf) * c_old + sigm(gi) * tanh_f(gg);
      float h_new = sigm(go) * tanh_f(c_new);
      c_io[off] = c_new;
      hbf[off] = f2bf(h_new);
      if (t == LL - 1) h_out[off] = h_new;
    }

    __threadfence();
    grid.sync();
  }
}

__global__ __launch_bounds__(256) void lstm_loss_part(
    const float* __restrict__ h, const float* __restrict__ tgt, float* __restrict__ partials)
{
  __shared__ float lds[4];
  int tid = threadIdx.x;
  float s = 0.f;
  int base = blockIdx.x * 1024 + tid;
#pragma unroll
  for (int q = 0; q < 4; ++q) {
    int idx = base + (q << 8);
    s += fabsf(h[idx] - tgt[idx]);
  }
#pragma unroll
  for (int off = 32; off > 0; off >>= 1) s += __shfl_down(s, off, 64);
  if ((tid & 63) == 0) lds[tid >> 6] = s;
  __syncthreads();
  if (tid == 0) partials[blockIdx.x] = lds[0] + lds[1] + lds[2] + lds[3];
}

__global__ __launch_bounds__(256) void lstm_loss_fin(
    const float* __restrict__ partials, float* __restrict__ out)
{
  __shared__ float lds[4];
  int tid = threadIdx.x;
  float s = partials[tid];
#pragma unroll
  for (int off = 32; off > 0; off >>= 1) s += __shfl_down(s, off, 64);
  if ((tid & 63) == 0) lds[tid >> 6] = s;
  __syncthreads();
  if (tid == 0) out[0] = (lds[0] + lds[1] + lds[2] + lds[3]) * (1.0f / 262144.0f);
}

extern "C" void kernel_launch(void* const* d_in, const int* in_sizes, int n_in,
                              void* d_out, int out_size, void* d_ws, size_t ws_size,
                              hipStream_t stream) {
  const float* x   = (const float*)d_in[0];
  const float* tgt = (const float*)d_in[1];
  const float* Wih = (const float*)d_in[2];
  const float* Whh = (const float*)d_in[3];

  float* out   = (float*)d_out;
  float* h_out = out + 1;                 // [256*1024]
  float* c_io  = out + 1 + BB * EE;       // [256*1024] running cell state

  // ws layout: Gx (134.2 MB) | xbf (16.8 MB) | hbf (0.5 MB) | partials
  float* Gx       = (float*)d_ws;
  short* xbf      = (short*)((char*)d_ws + (size_t)LL * BB * NG * 4);
  short* hbf      = (short*)((char*)xbf + (size_t)LL * BB * EE * 2);
  float* partials = (float*)((char*)hbf + (size_t)BB * EE * 2);

  lstm_prep<<<4096, 256, 0, stream>>>(x, xbf, c_io);
  lstm_gx<<<dim3(256, 32), 256, 0, stream>>>(xbf, Wih, Gx);

  {
    const float* GxA = Gx; const float* WhhA = Whh;
    short* hbfA = hbf; float* cA = c_io; float* hA = h_out;
    void* args[] = {&GxA, &WhhA, &hbfA, &cA, &hA};
    hipLaunchCooperativeKernel((void*)lstm_rec, dim3(256), dim3(512), args, 0, stream);
  }

  lstm_loss_part<<<256, 256, 0, stream>>>(h_out, tgt, partials);
  lstm_loss_fin<<<1, 256, 0, stream>>>(partials, out);
}

// Round 5
// 4014.201 us; speedup vs baseline: 1.0893x; 1.0893x over previous
//
#include <hip/hip_runtime.h>
#include <hip/hip_bf16.h>
#include <hip/hip_cooperative_groups.h>

namespace cg = cooperative_groups;

typedef __attribute__((ext_vector_type(8))) short bf16x8;
typedef __attribute__((ext_vector_type(4))) float f32x4;

static constexpr int BB = 256;   // batch
static constexpr int TT = 33;    // time (input)
static constexpr int EE = 1024;  // embed
static constexpr int LL = 32;    // scan steps = T-1
static constexpr int NG = 4096;  // 4*E gate rows

__device__ __forceinline__ short f2bf(float f) {
  unsigned u = __builtin_bit_cast(unsigned, f);
  u += 0x7fffu + ((u >> 16) & 1u);   // RNE
  return (short)(u >> 16);
}

__device__ __forceinline__ bf16x8 cvt8(f32x4 a, f32x4 b) {
  bf16x8 r;
  r[0] = f2bf(a[0]); r[1] = f2bf(a[1]); r[2] = f2bf(a[2]); r[3] = f2bf(a[3]);
  r[4] = f2bf(b[0]); r[5] = f2bf(b[1]); r[6] = f2bf(b[2]); r[7] = f2bf(b[3]);
  return r;
}

__device__ __forceinline__ float sigm(float x) { return 1.0f / (1.0f + __expf(-x)); }
__device__ __forceinline__ float tanh_f(float x) { return 1.0f - 2.0f / (__expf(2.0f * x) + 1.0f); }

// ---- prep: x fp32 -> bf16 [t][row][e] for t<32; c0 = x[:,1,:]
__global__ __launch_bounds__(256) void lstm_prep(
    const float* __restrict__ x, short* __restrict__ xbf, float* __restrict__ c_io)
{
  int g = blockIdx.x * 256 + threadIdx.x;      // 1,048,576 threads, 8 elems each
  int eb  = g & 127;
  int row = (g >> 7) & 255;
  int t   = g >> 15;
  const float* src = x + ((size_t)row * TT + t) * EE + (eb << 3);
  f32x4 lo = *(const f32x4*)src;
  f32x4 hi = *(const f32x4*)(src + 4);
  *(bf16x8*)(xbf + ((size_t)t * BB + row) * EE + (eb << 3)) = cvt8(lo, hi);
  if (t == 1) {
    float* cd = c_io + (size_t)row * EE + (eb << 3);
    *(f32x4*)cd = lo;
    *(f32x4*)(cd + 4) = hi;
  }
}

// ---- gx: G_x[t] = x_t @ W_ih[t]^T for ALL t at once. Grid (256, 32) x 256 thr.
__global__ __launch_bounds__(256) void lstm_gx(
    const short* __restrict__ xbf,   // [32][256][1024] bf16
    const float* __restrict__ Wih,   // [32][4096][1024]
    float* __restrict__ Gx)          // [32][256][4096]
{
  const int t    = blockIdx.y;
  const int tid  = threadIdx.x;
  const int lane = tid & 63;
  const int wv   = tid >> 6;      // gate 0..3
  const int lr   = lane & 15;
  const int kg   = lane >> 4;
  const int e0   = (blockIdx.x & 63) << 4;
  const int row0 = (blockIdx.x >> 6) << 6;

  f32x4 acc0{}, acc1{}, acc2{}, acc3{};

  const float* wp = Wih + (size_t)t * NG * EE + (size_t)(wv * EE + e0 + lr) * EE + (kg << 3);
  const short* a0 = xbf + ((size_t)t * BB + row0 +  0 + lr) * EE + (kg << 3);
  const short* a1 = a0 + 16 * EE;
  const short* a2 = a0 + 32 * EE;
  const short* a3 = a0 + 48 * EE;
#pragma unroll 4
  for (int kc = 0; kc < 32; ++kc) {
    bf16x8 bfr = cvt8(*(const f32x4*)wp, *(const f32x4*)(wp + 4));
    acc0 = __builtin_amdgcn_mfma_f32_16x16x32_bf16(*(const bf16x8*)a0, bfr, acc0, 0, 0, 0);
    acc1 = __builtin_amdgcn_mfma_f32_16x16x32_bf16(*(const bf16x8*)a1, bfr, acc1, 0, 0, 0);
    acc2 = __builtin_amdgcn_mfma_f32_16x16x32_bf16(*(const bf16x8*)a2, bfr, acc2, 0, 0, 0);
    acc3 = __builtin_amdgcn_mfma_f32_16x16x32_bf16(*(const bf16x8*)a3, bfr, acc3, 0, 0, 0);
    wp += 32; a0 += 32; a1 += 32; a2 += 32; a3 += 32;
  }

  const f32x4 av[4] = {acc0, acc1, acc2, acc3};
#pragma unroll
  for (int m = 0; m < 4; ++m)
#pragma unroll
    for (int j = 0; j < 4; ++j)
      Gx[((size_t)t * BB + row0 + (m << 4) + (kg << 2) + j) * NG + wv * EE + e0 + lr] = av[m][j];
}

// ---- rec: cooperative, 256 WGs x 512 thr (1 WG/CU — PROVEN coop config from round 2).
// XCD mapping: xcd = wg&7 owns e-slices [xcd*8, xcd*8+8) -> 2MB W/step per XCD L2.
// WG: 64 batch rows x 16 e-cols x 4 gates. Wave wv: gate wv&3, row-half wv>>2 (2 MFMA tiles).
// c register-resident (2/thread). h double-buffered in ws (write buf[t&1], read buf[(t-1)&1]).
// W_hh[t+1] L2-touched during step t: 4 rowgrp-WGs x 8 waves x 8KB cover each 256KB W slice.
__global__ __launch_bounds__(512) void lstm_rec(
    const float* __restrict__ Gx,    // [32][256][4096]
    const float* __restrict__ Whh,   // [32][4096][1024]
    short* __restrict__ hbf,         // [2][256][1024] bf16 double buffer
    float* __restrict__ c_io,        // [256][1024] fp32 (d_out c region)
    float* __restrict__ h_out)       // [256][1024] fp32 (d_out h region)
{
  cg::grid_group grid = cg::this_grid();
  __shared__ float lds_g[4][64][16];        // 16KB gate exchange
  __shared__ unsigned int lds_sink[256];    // 1KB touch sink

  const int tid  = threadIdx.x;
  const int lane = tid & 63;
  const int wv   = tid >> 6;      // 0..7
  const int g    = wv & 3;
  const int hf   = wv >> 2;       // row half (32 rows)
  const int lr   = lane & 15;
  const int kg   = lane >> 4;

  const int wg     = blockIdx.x;        // 0..255
  const int xcd    = wg & 7;
  const int jj     = wg >> 3;           // 0..31
  const int rowgrp = jj & 3;            // 4 x 64 rows
  const int ehi    = jj >> 2;           // 0..7
  const int e0     = (xcd * 8 + ehi) << 4;
  const int row0   = rowgrp << 6;

  // epilogue: 2 elements/thread (64 rows x 16 cols = 1024)
  const int rl0  = tid >> 4;            // 0..31
  const int er0  = row0 + rl0;
  const int er1  = er0 + 32;
  const int ecol = e0 + (tid & 15);
  float c0r = c_io[(size_t)er0 * EE + ecol];
  float c1r = c_io[(size_t)er1 * EE + ecol];

  for (int t = 0; t < LL; ++t) {
    short* h_wr = hbf + (size_t)(t & 1) * BB * EE;
    const short* h_rd = hbf + (size_t)((t + 1) & 1) * BB * EE;   // == (t-1)&1

    // Gx prefetch for epilogue (independent loads, consumed late)
    const float* gp0 = Gx + ((size_t)t * BB + er0) * NG + ecol;
    const float* gp1 = Gx + ((size_t)t * BB + er1) * NG + ecol;
    float gx00 = gp0[0], gx01 = gp0[EE], gx02 = gp0[2 * EE], gx03 = gp0[3 * EE];
    float gx10 = gp1[0], gx11 = gp1[EE], gx12 = gp1[2 * EE], gx13 = gp1[3 * EE];

    // touch W_hh[t+1]: (rowgrp,wv) picks a unique 8KB slice of the 256KB (e0) W region
    if (t + 1 < LL) {
      int v0  = (rowgrp << 16) + (wv << 13);       // byte offset in virtual 256KB region
      int blk = v0 >> 16;                          // gate block 0..3
      int off = v0 & 65535;                        // offset within 64KB gate slice
      const char* wsrc = (const char*)(Whh + ((size_t)(t + 1) * NG + (size_t)blk * EE + e0) * EE)
                       + off + lane * 16;
#pragma unroll
      for (int q = 0; q < 8; ++q)
        __builtin_amdgcn_global_load_lds(
            (const __attribute__((address_space(1))) unsigned int*)(wsrc + q * 1024),
            (__attribute__((address_space(3))) unsigned int*)lds_sink, 16, 0, 0);
    }

    f32x4 acc0{}, acc1{};
    if (t > 0) {
      const float* wp = Whh + (size_t)t * NG * EE + (size_t)(g * EE + e0 + lr) * EE + (kg << 3);
      const short* h0p = h_rd + (size_t)(row0 + hf * 32 + lr) * EE + (kg << 3);
      const short* h1p = h0p + 16 * EE;
#pragma unroll 4
      for (int kc = 0; kc < 32; ++kc) {
        bf16x8 bfr = cvt8(*(const f32x4*)wp, *(const f32x4*)(wp + 4));
        acc0 = __builtin_amdgcn_mfma_f32_16x16x32_bf16(*(const bf16x8*)h0p, bfr, acc0, 0, 0, 0);
        acc1 = __builtin_amdgcn_mfma_f32_16x16x32_bf16(*(const bf16x8*)h1p, bfr, acc1, 0, 0, 0);
        wp += 32; h0p += 32; h1p += 32;
      }
    }

#pragma unroll
    for (int j = 0; j < 4; ++j) {
      lds_g[g][hf * 32 +      (kg << 2) + j][lr] = acc0[j];
      lds_g[g][hf * 32 + 16 + (kg << 2) + j][lr] = acc1[j];
    }
    __syncthreads();

    {
      int el = tid & 15;
      // element 0 (rows 0..31 of WG)
      float gi = lds_g[0][rl0][el] + gx00;
      float gf = lds_g[1][rl0][el] + gx01;
      float gg = lds_g[2][rl0][el] + gx02;
      float go = lds_g[3][rl0][el] + gx03;
      c0r = sigm(gf) * c0r + sigm(gi) * tanh_f(gg);
      float h0n = sigm(go) * tanh_f(c0r);
      h_wr[(size_t)er0 * EE + ecol] = f2bf(h0n);
      // element 1 (rows 32..63)
      gi = lds_g[0][rl0 + 32][el] + gx10;
      gf = lds_g[1][rl0 + 32][el] + gx11;
      gg = lds_g[2][rl0 + 32][el] + gx12;
      go = lds_g[3][rl0 + 32][el] + gx13;
      c1r = sigm(gf) * c1r + sigm(gi) * tanh_f(gg);
      float h1n = sigm(go) * tanh_f(c1r);
      h_wr[(size_t)er1 * EE + ecol] = f2bf(h1n);

      if (t == LL - 1) {
        size_t o0 = (size_t)er0 * EE + ecol, o1 = (size_t)er1 * EE + ecol;
        h_out[o0] = h0n; c_io[o0] = c0r;
        h_out[o1] = h1n; c_io[o1] = c1r;
      }
    }

    __threadfence();
    grid.sync();
  }
}

__global__ __launch_bounds__(256) void lstm_loss_part(
    const float* __restrict__ h, const float* __restrict__ tgt, float* __restrict__ partials)
{
  __shared__ float lds[4];
  int tid = threadIdx.x;
  float s = 0.f;
  int base = blockIdx.x * 1024 + tid;
#pragma unroll
  for (int q = 0; q < 4; ++q) {
    int idx = base + (q << 8);
    s += fabsf(h[idx] - tgt[idx]);
  }
#pragma unroll
  for (int off = 32; off > 0; off >>= 1) s += __shfl_down(s, off, 64);
  if ((tid & 63) == 0) lds[tid >> 6] = s;
  __syncthreads();
  if (tid == 0) partials[blockIdx.x] = lds[0] + lds[1] + lds[2] + lds[3];
}

__global__ __launch_bounds__(256) void lstm_loss_fin(
    const float* __restrict__ partials, float* __restrict__ out)
{
  __shared__ float lds[4];
  int tid = threadIdx.x;
  float s = partials[tid];
#pragma unroll
  for (int off = 32; off > 0; off >>= 1) s += __shfl_down(s, off, 64);
  if ((tid & 63) == 0) lds[tid >> 6] = s;
  __syncthreads();
  if (tid == 0) out[0] = (lds[0] + lds[1] + lds[2] + lds[3]) * (1.0f / 262144.0f);
}

extern "C" void kernel_launch(void* const* d_in, const int* in_sizes, int n_in,
                              void* d_out, int out_size, void* d_ws, size_t ws_size,
                              hipStream_t stream) {
  const float* x   = (const float*)d_in[0];
  const float* tgt = (const float*)d_in[1];
  const float* Wih = (const float*)d_in[2];
  const float* Whh = (const float*)d_in[3];

  float* out   = (float*)d_out;
  float* h_out = out + 1;                 // [256*1024]
  float* c_io  = out + 1 + BB * EE;       // [256*1024]

  // ws layout: Gx (134.2 MB) | xbf (16.8 MB) | hbf[2] (1 MB) | partials
  float* Gx       = (float*)d_ws;
  short* xbf      = (short*)((char*)d_ws + (size_t)LL * BB * NG * 4);
  short* hbf      = (short*)((char*)xbf + (size_t)LL * BB * EE * 2);
  float* partials = (float*)((char*)hbf + (size_t)2 * BB * EE * 2);

  lstm_prep<<<4096, 256, 0, stream>>>(x, xbf, c_io);
  lstm_gx<<<dim3(256, 32), 256, 0, stream>>>(xbf, Wih, Gx);

  {
    const float* GxA = Gx; const float* WhhA = Whh;
    short* hbfA = hbf; float* cA = c_io; float* hA = h_out;
    void* args[] = {&GxA, &WhhA, &hbfA, &cA, &hA};
    hipLaunchCooperativeKernel((void*)lstm_rec, dim3(256), dim3(512), args, 0, stream);
  }

  lstm_loss_part<<<256, 256, 0, stream>>>(h_out, tgt, partials);
  lstm_loss_fin<<<1, 256, 0, stream>>>(partials, out);
}

// Round 6
// 3194.388 us; speedup vs baseline: 1.3689x; 1.2566x over previous
//
#include <hip/hip_runtime.h>
#include <hip/hip_bf16.h>

typedef __attribute__((ext_vector_type(8))) short bf16x8;
typedef __attribute__((ext_vector_type(4))) float f32x4;

static constexpr int BB = 256;   // batch
static constexpr int TT = 33;    // time (input)
static constexpr int EE = 1024;  // embed
static constexpr int LL = 32;    // scan steps = T-1
static constexpr int NG = 4096;  // 4*E gate rows

__device__ __forceinline__ short f2bf(float f) {
  unsigned u = __builtin_bit_cast(unsigned, f);
  u += 0x7fffu + ((u >> 16) & 1u);   // RNE
  return (short)(u >> 16);
}

__device__ __forceinline__ bf16x8 cvt8(f32x4 a, f32x4 b) {
  bf16x8 r;
  r[0] = f2bf(a[0]); r[1] = f2bf(a[1]); r[2] = f2bf(a[2]); r[3] = f2bf(a[3]);
  r[4] = f2bf(b[0]); r[5] = f2bf(b[1]); r[6] = f2bf(b[2]); r[7] = f2bf(b[3]);
  return r;
}

__device__ __forceinline__ float sigm(float x) { return 1.0f / (1.0f + __expf(-x)); }
__device__ __forceinline__ float tanh_f(float x) { return 1.0f - 2.0f / (__expf(2.0f * x) + 1.0f); }

// ---- prep: x fp32 -> bf16 [t][row][e] for t<32; c0 = x[:,1,:]; zero barriers
__global__ __launch_bounds__(256) void lstm_prep(
    const float* __restrict__ x, short* __restrict__ xbf, float* __restrict__ c_io,
    unsigned* __restrict__ bar)
{
  if (blockIdx.x == 0 && threadIdx.x < 4) bar[threadIdx.x] = 0;
  int g = blockIdx.x * 256 + threadIdx.x;      // 1,048,576 threads, 8 elems each
  int eb  = g & 127;
  int row = (g >> 7) & 255;
  int t   = g >> 15;
  const float* src = x + ((size_t)row * TT + t) * EE + (eb << 3);
  f32x4 lo = *(const f32x4*)src;
  f32x4 hi = *(const f32x4*)(src + 4);
  *(bf16x8*)(xbf + ((size_t)t * BB + row) * EE + (eb << 3)) = cvt8(lo, hi);
  if (t == 1) {
    float* cd = c_io + (size_t)row * EE + (eb << 3);
    *(f32x4*)cd = lo;
    *(f32x4*)(cd + 4) = hi;
  }
}

// ---- gx: G_x[t] = x_t @ W_ih[t]^T for ALL t at once. Grid (256, 32) x 256 thr.
__global__ __launch_bounds__(256) void lstm_gx(
    const short* __restrict__ xbf,   // [32][256][1024] bf16
    const float* __restrict__ Wih,   // [32][4096][1024]
    float* __restrict__ Gx)          // [32][256][4096]
{
  const int t    = blockIdx.y;
  const int tid  = threadIdx.x;
  const int lane = tid & 63;
  const int wv   = tid >> 6;      // gate 0..3
  const int lr   = lane & 15;
  const int kg   = lane >> 4;
  const int e0   = (blockIdx.x & 63) << 4;
  const int row0 = (blockIdx.x >> 6) << 6;

  f32x4 acc0{}, acc1{}, acc2{}, acc3{};

  const float* wp = Wih + (size_t)t * NG * EE + (size_t)(wv * EE + e0 + lr) * EE + (kg << 3);
  const short* a0 = xbf + ((size_t)t * BB + row0 +  0 + lr) * EE + (kg << 3);
  const short* a1 = a0 + 16 * EE;
  const short* a2 = a0 + 32 * EE;
  const short* a3 = a0 + 48 * EE;
#pragma unroll 4
  for (int kc = 0; kc < 32; ++kc) {
    bf16x8 bfr = cvt8(*(const f32x4*)wp, *(const f32x4*)(wp + 4));
    acc0 = __builtin_amdgcn_mfma_f32_16x16x32_bf16(*(const bf16x8*)a0, bfr, acc0, 0, 0, 0);
    acc1 = __builtin_amdgcn_mfma_f32_16x16x32_bf16(*(const bf16x8*)a1, bfr, acc1, 0, 0, 0);
    acc2 = __builtin_amdgcn_mfma_f32_16x16x32_bf16(*(const bf16x8*)a2, bfr, acc2, 0, 0, 0);
    acc3 = __builtin_amdgcn_mfma_f32_16x16x32_bf16(*(const bf16x8*)a3, bfr, acc3, 0, 0, 0);
    wp += 32; a0 += 32; a1 += 32; a2 += 32; a3 += 32;
  }

  const f32x4 av[4] = {acc0, acc1, acc2, acc3};
#pragma unroll
  for (int m = 0; m < 4; ++m)
#pragma unroll
    for (int j = 0; j < 4; ++j)
      Gx[((size_t)t * BB + row0 + (m << 4) + (kg << 2) + j) * NG + wv * EE + e0 + lr] = av[m][j];
}

// ---- rec: 256 WGs x 512 thr (coop launch for co-residency only — no grid.sync).
// Per-ROWGROUP barriers (4 groups of 64 WGs, monotonic counter in ws):
// consumer at step t needs h_{t-1} rows of its OWN rowgroup only.
// K-loop: explicit 2-deep register ping-pong (16 loads in flight/wave) with
// __launch_bounds__(512,1) so the compiler has VGPR room (~170), not 64.
__global__ __launch_bounds__(512, 1) void lstm_rec(
    const float* __restrict__ Gx,    // [32][256][4096]
    const float* __restrict__ Whh,   // [32][4096][1024]
    short* __restrict__ hbf,         // [2][256][1024] bf16 double buffer
    float* __restrict__ c_io,        // [256][1024] fp32 (d_out c region)
    float* __restrict__ h_out,       // [256][1024] fp32 (d_out h region)
    unsigned* __restrict__ bar)      // [4] rowgroup arrival counters
{
  __shared__ float lds_g[4][64][16];        // 16KB gate exchange

  const int tid  = threadIdx.x;
  const int lane = tid & 63;
  const int wv   = tid >> 6;      // 0..7
  const int g    = wv & 3;
  const int hf   = wv >> 2;       // row half (32 rows)
  const int lr   = lane & 15;
  const int kg   = lane >> 4;

  const int wg     = blockIdx.x;        // 0..255
  const int xcd    = wg & 7;
  const int jj     = wg >> 3;           // 0..31
  const int rowgrp = jj & 3;            // 4 x 64 rows
  const int ehi    = jj >> 2;           // 0..7
  const int e0     = (xcd * 8 + ehi) << 4;
  const int row0   = rowgrp << 6;

  const int rl0  = tid >> 4;            // 0..31
  const int er0  = row0 + rl0;
  const int er1  = er0 + 32;
  const int ecol = e0 + (tid & 15);
  float c0r = c_io[(size_t)er0 * EE + ecol];
  float c1r = c_io[(size_t)er1 * EE + ecol];

  for (int t = 0; t < LL; ++t) {
    short* h_wr = hbf + (size_t)(t & 1) * BB * EE;
    const short* h_rd = hbf + (size_t)((t + 1) & 1) * BB * EE;   // == (t-1)&1

    if (t > 0) {
      // rowgroup barrier wait: h_{t-1} of this rowgroup fully published
      if (tid == 0) {
        const unsigned tgt = 64u * (unsigned)t;
        while (__hip_atomic_load(&bar[rowgrp], __ATOMIC_ACQUIRE, __HIP_MEMORY_SCOPE_AGENT) < tgt)
          __builtin_amdgcn_s_sleep(2);
      }
      __syncthreads();
      __threadfence();                       // per-thread acquire insurance (inv)
      __builtin_amdgcn_sched_barrier(0);
    }

    // Gx prefetch for epilogue (independent loads, consumed late)
    const float* gp0 = Gx + ((size_t)t * BB + er0) * NG + ecol;
    const float* gp1 = Gx + ((size_t)t * BB + er1) * NG + ecol;
    float gx00 = gp0[0], gx01 = gp0[EE], gx02 = gp0[2 * EE], gx03 = gp0[3 * EE];
    float gx10 = gp1[0], gx11 = gp1[EE], gx12 = gp1[2 * EE], gx13 = gp1[3 * EE];

    f32x4 acc0{}, acc1{};
    if (t > 0) {
      const float* wp  = Whh + (size_t)t * NG * EE + (size_t)(g * EE + e0 + lr) * EE + (kg << 3);
      const short* h0p = h_rd + (size_t)(row0 + hf * 32 + lr) * EE + (kg << 3);
      const short* h1p = h0p + 16 * EE;

      f32x4 cw0[4], cw1[4]; bf16x8 ch0[4], ch1[4];
      f32x4 nw0[4], nw1[4]; bf16x8 nh0[4], nh1[4];
#pragma unroll
      for (int j = 0; j < 4; ++j) {
        cw0[j] = *(const f32x4*)(wp + j * 32);
        cw1[j] = *(const f32x4*)(wp + j * 32 + 4);
        ch0[j] = *(const bf16x8*)(h0p + j * 32);
        ch1[j] = *(const bf16x8*)(h1p + j * 32);
      }
#pragma unroll
      for (int grp = 0; grp < 8; ++grp) {
        if (grp < 7) {
          const int b = (grp + 1) * 128;     // 128 floats / 128 shorts = 4 k-chunks
#pragma unroll
          for (int j = 0; j < 4; ++j) {
            nw0[j] = *(const f32x4*)(wp + b + j * 32);
            nw1[j] = *(const f32x4*)(wp + b + j * 32 + 4);
            nh0[j] = *(const bf16x8*)(h0p + b + j * 32);
            nh1[j] = *(const bf16x8*)(h1p + b + j * 32);
          }
        }
#pragma unroll
        for (int j = 0; j < 4; ++j) {
          bf16x8 bfr = cvt8(cw0[j], cw1[j]);
          acc0 = __builtin_amdgcn_mfma_f32_16x16x32_bf16(ch0[j], bfr, acc0, 0, 0, 0);
          acc1 = __builtin_amdgcn_mfma_f32_16x16x32_bf16(ch1[j], bfr, acc1, 0, 0, 0);
        }
        if (grp < 7) {
#pragma unroll
          for (int j = 0; j < 4; ++j) {
            cw0[j] = nw0[j]; cw1[j] = nw1[j]; ch0[j] = nh0[j]; ch1[j] = nh1[j];
          }
        }
      }
    }

#pragma unroll
    for (int j = 0; j < 4; ++j) {
      lds_g[g][hf * 32 +      (kg << 2) + j][lr] = acc0[j];
      lds_g[g][hf * 32 + 16 + (kg << 2) + j][lr] = acc1[j];
    }
    __syncthreads();

    {
      int el = tid & 15;
      float gi = lds_g[0][rl0][el] + gx00;
      float gf = lds_g[1][rl0][el] + gx01;
      float gg = lds_g[2][rl0][el] + gx02;
      float go = lds_g[3][rl0][el] + gx03;
      c0r = sigm(gf) * c0r + sigm(gi) * tanh_f(gg);
      float h0n = sigm(go) * tanh_f(c0r);
      h_wr[(size_t)er0 * EE + ecol] = f2bf(h0n);

      gi = lds_g[0][rl0 + 32][el] + gx10;
      gf = lds_g[1][rl0 + 32][el] + gx11;
      gg = lds_g[2][rl0 + 32][el] + gx12;
      go = lds_g[3][rl0 + 32][el] + gx13;
      c1r = sigm(gf) * c1r + sigm(gi) * tanh_f(gg);
      float h1n = sigm(go) * tanh_f(c1r);
      h_wr[(size_t)er1 * EE + ecol] = f2bf(h1n);

      if (t == LL - 1) {
        size_t o0 = (size_t)er0 * EE + ecol, o1 = (size_t)er1 * EE + ecol;
        h_out[o0] = h0n; c_io[o0] = c0r;
        h_out[o1] = h1n; c_io[o1] = c1r;
      }
    }
    __syncthreads();   // drains all waves' h stores; lds_g consumed

    // rowgroup barrier arrive (release: writes back dirty L2 before flag)
    if (tid == 0)
      __hip_atomic_fetch_add(&bar[rowgrp], 1u, __ATOMIC_RELEASE, __HIP_MEMORY_SCOPE_AGENT);
  }
}

__global__ __launch_bounds__(256) void lstm_loss_part(
    const float* __restrict__ h, const float* __restrict__ tgt, float* __restrict__ partials)
{
  __shared__ float lds[4];
  int tid = threadIdx.x;
  float s = 0.f;
  int base = blockIdx.x * 1024 + tid;
#pragma unroll
  for (int q = 0; q < 4; ++q) {
    int idx = base + (q << 8);
    s += fabsf(h[idx] - tgt[idx]);
  }
#pragma unroll
  for (int off = 32; off > 0; off >>= 1) s += __shfl_down(s, off, 64);
  if ((tid & 63) == 0) lds[tid >> 6] = s;
  __syncthreads();
  if (tid == 0) partials[blockIdx.x] = lds[0] + lds[1] + lds[2] + lds[3];
}

__global__ __launch_bounds__(256) void lstm_loss_fin(
    const float* __restrict__ partials, float* __restrict__ out)
{
  __shared__ float lds[4];
  int tid = threadIdx.x;
  float s = partials[tid];
#pragma unroll
  for (int off = 32; off > 0; off >>= 1) s += __shfl_down(s, off, 64);
  if ((tid & 63) == 0) lds[tid >> 6] = s;
  __syncthreads();
  if (tid == 0) out[0] = (lds[0] + lds[1] + lds[2] + lds[3]) * (1.0f / 262144.0f);
}

extern "C" void kernel_launch(void* const* d_in, const int* in_sizes, int n_in,
                              void* d_out, int out_size, void* d_ws, size_t ws_size,
                              hipStream_t stream) {
  const float* x   = (const float*)d_in[0];
  const float* tgt = (const float*)d_in[1];
  const float* Wih = (const float*)d_in[2];
  const float* Whh = (const float*)d_in[3];

  float* out   = (float*)d_out;
  float* h_out = out + 1;                 // [256*1024]
  float* c_io  = out + 1 + BB * EE;       // [256*1024]

  // ws layout: Gx (134.2 MB) | xbf (16.8 MB) | hbf[2] (1 MB) | partials (1KB) | bar (4)
  float* Gx       = (float*)d_ws;
  short* xbf      = (short*)((char*)d_ws + (size_t)LL * BB * NG * 4);
  short* hbf      = (short*)((char*)xbf + (size_t)LL * BB * EE * 2);
  float* partials = (float*)((char*)hbf + (size_t)2 * BB * EE * 2);
  unsigned* bar   = (unsigned*)((char*)partials + 1024);

  lstm_prep<<<4096, 256, 0, stream>>>(x, xbf, c_io, bar);
  lstm_gx<<<dim3(256, 32), 256, 0, stream>>>(xbf, Wih, Gx);

  {
    const float* GxA = Gx; const float* WhhA = Whh;
    short* hbfA = hbf; float* cA = c_io; float* hA = h_out;
    unsigned* barA = bar;
    void* args[] = {&GxA, &WhhA, &hbfA, &cA, &hA, &barA};
    hipLaunchCooperativeKernel((void*)lstm_rec, dim3(256), dim3(512), args, 0, stream);
  }

  lstm_loss_part<<<256, 256, 0, stream>>>(h_out, tgt, partials);
  lstm_loss_fin<<<1, 256, 0, stream>>>(partials, out);
}

// Round 7
// 2156.204 us; speedup vs baseline: 2.0279x; 1.4815x over previous
//
#include <hip/hip_runtime.h>
#include <hip/hip_bf16.h>

typedef __attribute__((ext_vector_type(8))) short bf16x8;
typedef __attribute__((ext_vector_type(4))) float f32x4;

static constexpr int BB = 256;   // batch
static constexpr int TT = 33;    // time (input)
static constexpr int EE = 1024;  // embed
static constexpr int LL = 32;    // scan steps = T-1
static constexpr int NG = 4096;  // 4*E gate rows

__device__ __forceinline__ short f2bf(float f) {
  unsigned u = __builtin_bit_cast(unsigned, f);
  u += 0x7fffu + ((u >> 16) & 1u);   // RNE
  return (short)(u >> 16);
}

__device__ __forceinline__ bf16x8 cvt8(f32x4 a, f32x4 b) {
  bf16x8 r;
  r[0] = f2bf(a[0]); r[1] = f2bf(a[1]); r[2] = f2bf(a[2]); r[3] = f2bf(a[3]);
  r[4] = f2bf(b[0]); r[5] = f2bf(b[1]); r[6] = f2bf(b[2]); r[7] = f2bf(b[3]);
  return r;
}

// coherent 16B h-fragment load: two 8B agent-scope relaxed atomics (sc1, L2-bypass)
__device__ __forceinline__ bf16x8 h16(const short* p) {
  const unsigned long long* q = (const unsigned long long*)p;
  unsigned long long a = __hip_atomic_load(q,     __ATOMIC_RELAXED, __HIP_MEMORY_SCOPE_AGENT);
  unsigned long long b = __hip_atomic_load(q + 1, __ATOMIC_RELAXED, __HIP_MEMORY_SCOPE_AGENT);
  struct S { unsigned long long a, b; } s{a, b};
  return __builtin_bit_cast(bf16x8, s);
}

__device__ __forceinline__ float sigm(float x) { return 1.0f / (1.0f + __expf(-x)); }
__device__ __forceinline__ float tanh_f(float x) { return 1.0f - 2.0f / (__expf(2.0f * x) + 1.0f); }

// ---- prep: x fp32 -> bf16; c0 = x[:,1,:]; zero flags
__global__ __launch_bounds__(256) void lstm_prep(
    const float* __restrict__ x, short* __restrict__ xbf, float* __restrict__ c_io,
    unsigned* __restrict__ flags)
{
  if (blockIdx.x == 0) flags[threadIdx.x * 64] = 0;   // 256 slots, 256B apart
  int g = blockIdx.x * 256 + threadIdx.x;
  int eb  = g & 127;
  int row = (g >> 7) & 255;
  int t   = g >> 15;
  const float* src = x + ((size_t)row * TT + t) * EE + (eb << 3);
  f32x4 lo = *(const f32x4*)src;
  f32x4 hi = *(const f32x4*)(src + 4);
  *(bf16x8*)(xbf + ((size_t)t * BB + row) * EE + (eb << 3)) = cvt8(lo, hi);
  if (t == 1) {
    float* cd = c_io + (size_t)row * EE + (eb << 3);
    *(f32x4*)cd = lo;
    *(f32x4*)(cd + 4) = hi;
  }
}

// ---- gx: G_x[t] = x_t @ W_ih[t]^T for all t. Grid (256, 32) x 256 thr.
__global__ __launch_bounds__(256) void lstm_gx(
    const short* __restrict__ xbf,   // [32][256][1024] bf16
    const float* __restrict__ Wih,   // [32][4096][1024]
    float* __restrict__ Gx)          // [32][256][4096]
{
  const int t    = blockIdx.y;
  const int tid  = threadIdx.x;
  const int lane = tid & 63;
  const int wv   = tid >> 6;
  const int lr   = lane & 15;
  const int kg   = lane >> 4;
  const int e0   = (blockIdx.x & 63) << 4;
  const int row0 = (blockIdx.x >> 6) << 6;

  f32x4 acc0{}, acc1{}, acc2{}, acc3{};

  const float* wp = Wih + (size_t)t * NG * EE + (size_t)(wv * EE + e0 + lr) * EE + (kg << 3);
  const short* a0 = xbf + ((size_t)t * BB + row0 +  0 + lr) * EE + (kg << 3);
  const short* a1 = a0 + 16 * EE;
  const short* a2 = a0 + 32 * EE;
  const short* a3 = a0 + 48 * EE;
#pragma unroll 4
  for (int kc = 0; kc < 32; ++kc) {
    bf16x8 bfr = cvt8(*(const f32x4*)wp, *(const f32x4*)(wp + 4));
    acc0 = __builtin_amdgcn_mfma_f32_16x16x32_bf16(*(const bf16x8*)a0, bfr, acc0, 0, 0, 0);
    acc1 = __builtin_amdgcn_mfma_f32_16x16x32_bf16(*(const bf16x8*)a1, bfr, acc1, 0, 0, 0);
    acc2 = __builtin_amdgcn_mfma_f32_16x16x32_bf16(*(const bf16x8*)a2, bfr, acc2, 0, 0, 0);
    acc3 = __builtin_amdgcn_mfma_f32_16x16x32_bf16(*(const bf16x8*)a3, bfr, acc3, 0, 0, 0);
    wp += 32; a0 += 32; a1 += 32; a2 += 32; a3 += 32;
  }

  const f32x4 av[4] = {acc0, acc1, acc2, acc3};
#pragma unroll
  for (int m = 0; m < 4; ++m)
#pragma unroll
    for (int j = 0; j < 4; ++j)
      Gx[((size_t)t * BB + row0 + (m << 4) + (kg << 2) + j) * NG + wv * EE + e0 + lr] = av[m][j];
}

// ---- rec: 256 WGs x 512 thr, coop (co-residency only).
// Sync: per-WG flag on own 256B line; consumers poll 64 flags in PARALLEL (no RMW).
// h + flags move via agent-scope relaxed atomics (sc1: bypass XCD-L2, coherent in L3)
// -> no fences, no L2 invalidation -> W prefetched into L2 survives the step boundary.
__global__ __launch_bounds__(512) void lstm_rec(
    const float* __restrict__ Gx,    // [32][256][4096]
    const float* __restrict__ Whh,   // [32][4096][1024]
    short* __restrict__ hbf,         // [2][256][1024] bf16 double buffer (sc1 access)
    float* __restrict__ c_io,        // [256][1024] fp32 (d_out c region)
    float* __restrict__ h_out,       // [256][1024] fp32 (d_out h region)
    unsigned* __restrict__ flags)    // [4][64] slots, 64-uint (256B) spacing
{
  __shared__ float lds_g[4][64][16];        // 16KB gate exchange
  __shared__ short lds_h[64][16];           // 2KB h tile (for 8B coherent stores)
  __shared__ unsigned int lds_sink[256];    // 1KB touch sink

  const int tid  = threadIdx.x;
  const int lane = tid & 63;
  const int wv   = tid >> 6;      // 0..7
  const int g    = wv & 3;
  const int hf   = wv >> 2;
  const int lr   = lane & 15;
  const int kg   = lane >> 4;

  const int wg     = blockIdx.x;        // 0..255
  const int xcd    = wg & 7;
  const int jj     = wg >> 3;           // 0..31
  const int rowgrp = jj & 3;            // 4 x 64 rows
  const int ehi    = jj >> 2;           // 0..7
  const int es     = xcd * 8 + ehi;     // e-slice id 0..63
  const int e0     = es << 4;
  const int row0   = rowgrp << 6;

  const int rl0  = tid >> 4;            // 0..31
  const int er0  = row0 + rl0;
  const int er1  = er0 + 32;
  const int ecol = e0 + (tid & 15);
  float c0r = c_io[(size_t)er0 * EE + ecol];
  float c1r = c_io[(size_t)er1 * EE + ecol];

  unsigned* myflag = flags + (size_t)(rowgrp * 64 + es) * 64;
  unsigned* grpflags = flags + (size_t)(rowgrp * 64) * 64;

  for (int t = 0; t < LL; ++t) {
    short* h_wr = hbf + (size_t)(t & 1) * BB * EE;
    const short* h_rd = hbf + (size_t)((t + 1) & 1) * BB * EE;

    // ---- independent work first: Gx loads + W[t+1] L2 touch (overlap the flag wait)
    const float* gp0 = Gx + ((size_t)t * BB + er0) * NG + ecol;
    const float* gp1 = Gx + ((size_t)t * BB + er1) * NG + ecol;
    float gx00 = gp0[0], gx01 = gp0[EE], gx02 = gp0[2 * EE], gx03 = gp0[3 * EE];
    float gx10 = gp1[0], gx11 = gp1[EE], gx12 = gp1[2 * EE], gx13 = gp1[3 * EE];

    if (t + 1 < LL) {
      int v0  = (rowgrp << 16) + (wv << 13);       // unique 8KB of this e-slice's 256KB
      int blk = v0 >> 16;
      int off = v0 & 65535;
      const char* wsrc = (const char*)(Whh + ((size_t)(t + 1) * NG + (size_t)blk * EE + e0) * EE)
                       + off + lane * 16;
#pragma unroll
      for (int q = 0; q < 8; ++q)
        __builtin_amdgcn_global_load_lds(
            (const __attribute__((address_space(1))) unsigned int*)(wsrc + q * 1024),
            (__attribute__((address_space(3))) unsigned int*)lds_sink, 16, 0, 0);
    }

    // ---- flag wait: h_{t-1} of this rowgroup published (parallel poll, 1 flag/thread)
    if (t > 0) {
      if (tid < 64) {
        while (__hip_atomic_load(grpflags + (size_t)tid * 64,
                                 __ATOMIC_RELAXED, __HIP_MEMORY_SCOPE_AGENT) < (unsigned)t)
          __builtin_amdgcn_s_sleep(1);
      }
      __syncthreads();
      __builtin_amdgcn_sched_barrier(0);
    }

    f32x4 acc0{}, acc1{};
    if (t > 0) {
      const float* wp  = Whh + (size_t)t * NG * EE + (size_t)(g * EE + e0 + lr) * EE + (kg << 3);
      const short* h0p = h_rd + (size_t)(row0 + hf * 32 + lr) * EE + (kg << 3);
      const short* h1p = h0p + 16 * EE;
#pragma unroll 4
      for (int kc = 0; kc < 32; ++kc) {
        bf16x8 bfr = cvt8(*(const f32x4*)wp, *(const f32x4*)(wp + 4));
        acc0 = __builtin_amdgcn_mfma_f32_16x16x32_bf16(h16(h0p), bfr, acc0, 0, 0, 0);
        acc1 = __builtin_amdgcn_mfma_f32_16x16x32_bf16(h16(h1p), bfr, acc1, 0, 0, 0);
        wp += 32; h0p += 32; h1p += 32;
      }
    }

#pragma unroll
    for (int j = 0; j < 4; ++j) {
      lds_g[g][hf * 32 +      (kg << 2) + j][lr] = acc0[j];
      lds_g[g][hf * 32 + 16 + (kg << 2) + j][lr] = acc1[j];
    }
    __syncthreads();

    {
      int el = tid & 15;
      float gi = lds_g[0][rl0][el] + gx00;
      float gf = lds_g[1][rl0][el] + gx01;
      float gg = lds_g[2][rl0][el] + gx02;
      float go = lds_g[3][rl0][el] + gx03;
      c0r = sigm(gf) * c0r + sigm(gi) * tanh_f(gg);
      float h0n = sigm(go) * tanh_f(c0r);
      lds_h[rl0][el] = f2bf(h0n);

      gi = lds_g[0][rl0 + 32][el] + gx10;
      gf = lds_g[1][rl0 + 32][el] + gx11;
      gg = lds_g[2][rl0 + 32][el] + gx12;
      go = lds_g[3][rl0 + 32][el] + gx13;
      c1r = sigm(gf) * c1r + sigm(gi) * tanh_f(gg);
      float h1n = sigm(go) * tanh_f(c1r);
      lds_h[rl0 + 32][el] = f2bf(h1n);

      if (t == LL - 1) {
        size_t o0 = (size_t)er0 * EE + ecol, o1 = (size_t)er1 * EE + ecol;
        h_out[o0] = h0n; c_io[o0] = c0r;
        h_out[o1] = h1n; c_io[o1] = c1r;
      }
    }
    __syncthreads();   // lds_h complete; lds_g consumed

    // ---- publish h: coherent 8B stores (sc1), drain, then flag store
    if (tid < 256) {
      int r = tid >> 2, c4 = (tid & 3) << 2;
      unsigned long long v = *(unsigned long long*)&lds_h[r][c4];
      __hip_atomic_store((unsigned long long*)(h_wr + (size_t)(row0 + r) * EE + e0 + c4), v,
                         __ATOMIC_RELAXED, __HIP_MEMORY_SCOPE_AGENT);
    }
    asm volatile("s_waitcnt vmcnt(0)" ::: "memory");   // h stores at coherence point
    __syncthreads();                                   // all waves drained
    if (tid == 0)
      __hip_atomic_store(myflag, (unsigned)(t + 1),
                         __ATOMIC_RELAXED, __HIP_MEMORY_SCOPE_AGENT);
    __syncthreads();   // keep lds_h/lds_g stable until publish done
  }
}

__global__ __launch_bounds__(256) void lstm_loss_part(
    const float* __restrict__ h, const float* __restrict__ tgt, float* __restrict__ partials)
{
  __shared__ float lds[4];
  int tid = threadIdx.x;
  float s = 0.f;
  int base = blockIdx.x * 1024 + tid;
#pragma unroll
  for (int q = 0; q < 4; ++q) {
    int idx = base + (q << 8);
    s += fabsf(h[idx] - tgt[idx]);
  }
#pragma unroll
  for (int off = 32; off > 0; off >>= 1) s += __shfl_down(s, off, 64);
  if ((tid & 63) == 0) lds[tid >> 6] = s;
  __syncthreads();
  if (tid == 0) partials[blockIdx.x] = lds[0] + lds[1] + lds[2] + lds[3];
}

__global__ __launch_bounds__(256) void lstm_loss_fin(
    const float* __restrict__ partials, float* __restrict__ out)
{
  __shared__ float lds[4];
  int tid = threadIdx.x;
  float s = partials[tid];
#pragma unroll
  for (int off = 32; off > 0; off >>= 1) s += __shfl_down(s, off, 64);
  if ((tid & 63) == 0) lds[tid >> 6] = s;
  __syncthreads();
  if (tid == 0) out[0] = (lds[0] + lds[1] + lds[2] + lds[3]) * (1.0f / 262144.0f);
}

extern "C" void kernel_launch(void* const* d_in, const int* in_sizes, int n_in,
                              void* d_out, int out_size, void* d_ws, size_t ws_size,
                              hipStream_t stream) {
  const float* x   = (const float*)d_in[0];
  const float* tgt = (const float*)d_in[1];
  const float* Wih = (const float*)d_in[2];
  const float* Whh = (const float*)d_in[3];

  float* out   = (float*)d_out;
  float* h_out = out + 1;                 // [256*1024]
  float* c_io  = out + 1 + BB * EE;       // [256*1024]

  // ws: Gx (134.2MB) | xbf (16.8MB) | hbf[2] (1MB) | partials (1KB) | flags (64KB)
  float* Gx       = (float*)d_ws;
  short* xbf      = (short*)((char*)d_ws + (size_t)LL * BB * NG * 4);
  short* hbf      = (short*)((char*)xbf + (size_t)LL * BB * EE * 2);
  float* partials = (float*)((char*)hbf + (size_t)2 * BB * EE * 2);
  unsigned* flags = (unsigned*)((char*)partials + 1024);

  lstm_prep<<<4096, 256, 0, stream>>>(x, xbf, c_io, flags);
  lstm_gx<<<dim3(256, 32), 256, 0, stream>>>(xbf, Wih, Gx);

  {
    const float* GxA = Gx; const float* WhhA = Whh;
    short* hbfA = hbf; float* cA = c_io; float* hA = h_out;
    unsigned* flagsA = flags;
    void* args[] = {&GxA, &WhhA, &hbfA, &cA, &hA, &flagsA};
    hipLaunchCooperativeKernel((void*)lstm_rec, dim3(256), dim3(512), args, 0, stream);
  }

  lstm_loss_part<<<256, 256, 0, stream>>>(h_out, tgt, partials);
  lstm_loss_fin<<<1, 256, 0, stream>>>(partials, out);
}

// Round 8
// 684.419 us; speedup vs baseline: 6.3888x; 3.1504x over previous
//
#include <hip/hip_runtime.h>
#include <hip/hip_bf16.h>

typedef __attribute__((ext_vector_type(8))) short bf16x8;
typedef __attribute__((ext_vector_type(4))) float f32x4;

static constexpr int BB = 256;   // batch
static constexpr int TT = 33;    // time (input)
static constexpr int EE = 1024;  // embed
static constexpr int LL = 32;    // scan steps = T-1
static constexpr int NG = 4096;  // 4*E gate rows

__device__ __forceinline__ short f2bf(float f) {
  unsigned u = __builtin_bit_cast(unsigned, f);
  u += 0x7fffu + ((u >> 16) & 1u);   // RNE
  return (short)(u >> 16);
}

__device__ __forceinline__ bf16x8 cvt8(f32x4 a, f32x4 b) {
  bf16x8 r;
  r[0] = f2bf(a[0]); r[1] = f2bf(a[1]); r[2] = f2bf(a[2]); r[3] = f2bf(a[3]);
  r[4] = f2bf(b[0]); r[5] = f2bf(b[1]); r[6] = f2bf(b[2]); r[7] = f2bf(b[3]);
  return r;
}

__device__ __forceinline__ float sigm(float x) { return 1.0f / (1.0f + __expf(-x)); }
__device__ __forceinline__ float tanh_f(float x) { return 1.0f - 2.0f / (__expf(2.0f * x) + 1.0f); }

// ---- prep: x fp32 -> bf16 [t][row][e]; c0 = x[:,1,:]; zero 256 flags
__global__ __launch_bounds__(256) void lstm_prep(
    const float* __restrict__ x, short* __restrict__ xbf, float* __restrict__ c_io,
    unsigned* __restrict__ flags)
{
  if (blockIdx.x == 0) flags[(size_t)threadIdx.x * 64] = 0;   // 256 slots, 256B apart
  int gth = blockIdx.x * 256 + threadIdx.x;
  int eb  = gth & 127;
  int row = (gth >> 7) & 255;
  int t   = gth >> 15;
  const float* src = x + ((size_t)row * TT + t) * EE + (eb << 3);
  f32x4 lo = *(const f32x4*)src;
  f32x4 hi = *(const f32x4*)(src + 4);
  *(bf16x8*)(xbf + ((size_t)t * BB + row) * EE + (eb << 3)) = cvt8(lo, hi);
  if (t == 1) {
    float* cd = c_io + (size_t)row * EE + (eb << 3);
    *(f32x4*)cd = lo;
    *(f32x4*)(cd + 4) = hi;
  }
}

// ---- rec: 256 WGs x 512 thr, cooperative (co-residency; no grid.sync).
// Per step: 32 chunks (BK=64): chunks 0-15 = x_t@Wih^T (flag-free), 16-31 = h@Whh^T.
// Staging: global_load_lds double-buffered, counted vmcnt(3), raw s_barrier (no
// __syncthreads in hot loop -> no vmcnt(0) drains). W/A LDS XOR-swizzled for
// conflict-free ds_read (swizzle applied on pre-swizzled global source, linear dest).
// h: 32 ROTATING buffers -> plain cached staged reads are never stale (address
// written once via sc1->L3, read once; dispatch-start invalidate covers replays).
// Sync: per-WG flag (256B line) sc1 store after vmcnt-drained sc1 h-publish;
// consumers poll all 256 flags in parallel (keeps rowgroups lockstepped for L2 W-dedup).
__global__ __launch_bounds__(512) void lstm_rec(
    const short* __restrict__ xbf,   // [32][256][1024] bf16
    const float* __restrict__ Wih,   // [32][4096][1024]
    const float* __restrict__ Whh,   // [32][4096][1024]
    short* __restrict__ hroll,       // [32][256][1024] bf16 rotating
    float* __restrict__ c_io,        // [256][1024] fp32 (d_out c region)
    float* __restrict__ h_out,       // [256][1024] fp32 (d_out h region)
    unsigned* __restrict__ flags)    // [256] slots, 64-uint spacing
{
  // LDS map: [0,16K) Wbuf0 | [16K,32K) Wbuf1 | [32K,40K) Abuf0 | [40K,48K) Abuf1
  // epilogue aliases: ldsg (16KB) on Wbuf0, hh (2KB) on Wbuf1 — both free then.
  __shared__ __align__(16) char smem[49152];

  const int tid  = threadIdx.x;
  const int lane = tid & 63;
  const int wv   = tid >> 6;      // 0..7
  const int g    = wv & 3;        // gate
  const int hf   = wv >> 2;       // row half (32 rows)
  const int lr   = lane & 15;
  const int kg   = lane >> 4;

  const int wg     = blockIdx.x;        // 0..255
  const int xcd    = wg & 7;
  const int jj     = wg >> 3;
  const int rowgrp = jj & 3;            // 4 x 64 rows
  const int ehi    = jj >> 2;           // 0..7
  const int e0     = (xcd * 8 + ehi) << 4;
  const int row0   = rowgrp << 6;

  const int rowW  = g * 16 + lr;
  const int mw    = ((lr & 7) << 5) | ((lr & 8) << 1);   // W swizzle mask (row bits)
  const int ma    = (lr & 7) << 4;                       // A swizzle mask
  const int arow0 = hf * 32 + lr;

  const int rl0  = tid >> 4;            // 0..31
  const int ecol = e0 + (tid & 15);
  float c0r = c_io[(size_t)(row0 + rl0) * EE + ecol];
  float c1r = c_io[(size_t)(row0 + rl0 + 32) * EE + ecol];

  f32x4 acc0{}, acc1{};

  auto stage = [&](int tt, int cc) {
    const int p   = cc >> 4;            // 0: x@Wih, 1: h@Whh
    const int k0  = (cc & 15) << 6;     // k offset (elements)
    const int buf = cc & 1;
    const char* Wt = (const char*)((p ? Whh : Wih) + (size_t)tt * NG * EE);
    const char* At = p ? (const char*)(hroll + (size_t)(tt - 1) * BB * EE)
                       : (const char*)(xbf + (size_t)tt * BB * EE);
#pragma unroll
    for (int r = 0; r < 2; ++r) {       // W chunk: 16KB fp32, linear dest, swz source
      int o = r * 8192 + wv * 1024 + lane * 16;
      int lrow = o >> 8;
      int mwr = ((lrow & 7) << 5) | ((lrow & 8) << 1);
      const char* src = Wt + (size_t)((lrow >> 4) * EE + e0 + (lrow & 15)) * 4096
                           + (size_t)(k0 << 2) + ((o & 255) ^ mwr);
      __builtin_amdgcn_global_load_lds(
          (const __attribute__((address_space(1))) unsigned int*)src,
          (__attribute__((address_space(3))) unsigned int*)(smem + buf * 16384 + r * 8192 + wv * 1024),
          16, 0, 0);
    }
    {                                   // A chunk: 8KB bf16
      int o = wv * 1024 + lane * 16;
      int lrow = o >> 7;
      const char* src = At + (size_t)(row0 + lrow) * 2048 + (size_t)(k0 << 1)
                           + ((o & 127) ^ ((lrow & 7) << 4));
      __builtin_amdgcn_global_load_lds(
          (const __attribute__((address_space(1))) unsigned int*)src,
          (__attribute__((address_space(3))) unsigned int*)(smem + 32768 + buf * 8192 + wv * 1024),
          16, 0, 0);
    }
  };

  auto compute = [&](int buf) {
    const char* Wb = smem + buf * 16384;
    const char* Ab = smem + 32768 + buf * 8192;
#pragma unroll
    for (int kit = 0; kit < 2; ++kit) {
      int u5 = (kit * 4 + kg) << 5;
      f32x4 wlo = *(const f32x4*)(Wb + rowW * 256 + ((u5) ^ mw));
      f32x4 whi = *(const f32x4*)(Wb + rowW * 256 + ((u5 | 16) ^ mw));
      bf16x8 bfr = cvt8(wlo, whi);
      int u4 = ((kit * 4 + kg) << 4) ^ ma;
      bf16x8 a0 = *(const bf16x8*)(Ab + arow0 * 128 + u4);
      bf16x8 a1 = *(const bf16x8*)(Ab + (arow0 + 16) * 128 + u4);
      acc0 = __builtin_amdgcn_mfma_f32_16x16x32_bf16(a0, bfr, acc0, 0, 0, 0);
      acc1 = __builtin_amdgcn_mfma_f32_16x16x32_bf16(a1, bfr, acc1, 0, 0, 0);
    }
  };

  stage(0, 0);
  stage(0, 1);

  for (int t = 0; t < LL; ++t) {
    const int nch = t ? 32 : 16;
    for (int c = 0; c < nch; ++c) {
      if (c == nch - 1) { asm volatile("s_waitcnt vmcnt(0)" ::: "memory"); }
      else             { asm volatile("s_waitcnt vmcnt(3)" ::: "memory"); }
      __builtin_amdgcn_s_barrier();
      compute(c & 1);
      __builtin_amdgcn_s_barrier();
      if (c + 2 < nch) {
        if (t > 0 && c == 14) {    // gate phase-B staging on h[t-1] publication
          if (tid < 256) {
            while (__hip_atomic_load(flags + (size_t)tid * 64,
                                     __ATOMIC_RELAXED, __HIP_MEMORY_SCOPE_AGENT) < (unsigned)t)
              __builtin_amdgcn_s_sleep(1);
          }
          __builtin_amdgcn_s_barrier();
          __builtin_amdgcn_sched_barrier(0);
        }
        stage(t, c + 2);
      }
    }

    // ---- epilogue: gate exchange (ldsg aliases Wbuf0), fused LSTM update
    float* ldsg = (float*)smem;
#pragma unroll
    for (int j = 0; j < 4; ++j) {
      ldsg[(g * 64 + hf * 32 + (kg << 2) + j) * 16 + lr] = acc0[j];
      ldsg[(g * 64 + hf * 32 + 16 + (kg << 2) + j) * 16 + lr] = acc1[j];
    }
    acc0 = f32x4{}; acc1 = f32x4{};
    asm volatile("s_waitcnt lgkmcnt(0)" ::: "memory");
    __builtin_amdgcn_s_barrier();

    {
      int el = tid & 15;
      float gi0 = ldsg[(0 * 64 + rl0) * 16 + el];
      float gf0 = ldsg[(1 * 64 + rl0) * 16 + el];
      float gg0 = ldsg[(2 * 64 + rl0) * 16 + el];
      float go0 = ldsg[(3 * 64 + rl0) * 16 + el];
      float gi1 = ldsg[(0 * 64 + rl0 + 32) * 16 + el];
      float gf1 = ldsg[(1 * 64 + rl0 + 32) * 16 + el];
      float gg1 = ldsg[(2 * 64 + rl0 + 32) * 16 + el];
      float go1 = ldsg[(3 * 64 + rl0 + 32) * 16 + el];

      c0r = sigm(gf0) * c0r + sigm(gi0) * tanh_f(gg0);
      float h0n = sigm(go0) * tanh_f(c0r);
      c1r = sigm(gf1) * c1r + sigm(gi1) * tanh_f(gg1);
      float h1n = sigm(go1) * tanh_f(c1r);

      short* hh = (short*)(smem + 16384);   // alias Wbuf1 (free after compute of last chunk)
      hh[rl0 * 16 + el] = f2bf(h0n);
      hh[(rl0 + 32) * 16 + el] = f2bf(h1n);

      if (t == LL - 1) {
        size_t o0 = (size_t)(row0 + rl0) * EE + ecol;
        size_t o1 = (size_t)(row0 + rl0 + 32) * EE + ecol;
        h_out[o0] = h0n; c_io[o0] = c0r;
        h_out[o1] = h1n; c_io[o1] = c1r;
      }
    }
    asm volatile("s_waitcnt lgkmcnt(0)" ::: "memory");
    __builtin_amdgcn_s_barrier();

    // ---- publish h[t]: sc1 8B stores (L2-bypass -> L3)
    if (tid < 256) {
      int r = tid >> 2, q = tid & 3;
      unsigned long long v = *(const unsigned long long*)(smem + 16384 + r * 32 + q * 8);
      __hip_atomic_store(
          (unsigned long long*)((char*)hroll + ((size_t)t * BB + row0 + r) * 2048 + (size_t)e0 * 2 + q * 8),
          v, __ATOMIC_RELAXED, __HIP_MEMORY_SCOPE_AGENT);
    }
    __builtin_amdgcn_s_barrier();   // all pub ds-reads retired before buffers restaged

    if (t < LL - 1) {
      stage(t + 1, 0);              // next step phase A (Wih/x): flag-free prefetch
      stage(t + 1, 1);
      asm volatile("s_waitcnt vmcnt(6)" ::: "memory");   // FIFO: retires pub stores
      __builtin_amdgcn_s_barrier();
      if (tid == 0)
        __hip_atomic_store(flags + (size_t)wg * 64, (unsigned)(t + 1),
                           __ATOMIC_RELAXED, __HIP_MEMORY_SCOPE_AGENT);
    } else {
      asm volatile("s_waitcnt vmcnt(0)" ::: "memory");
    }
  }
}

__global__ __launch_bounds__(256) void lstm_loss_part(
    const float* __restrict__ h, const float* __restrict__ tgt, float* __restrict__ partials)
{
  __shared__ float lds[4];
  int tid = threadIdx.x;
  float s = 0.f;
  int base = blockIdx.x * 1024 + tid;
#pragma unroll
  for (int q = 0; q < 4; ++q) {
    int idx = base + (q << 8);
    s += fabsf(h[idx] - tgt[idx]);
  }
#pragma unroll
  for (int off = 32; off > 0; off >>= 1) s += __shfl_down(s, off, 64);
  if ((tid & 63) == 0) lds[tid >> 6] = s;
  __syncthreads();
  if (tid == 0) partials[blockIdx.x] = lds[0] + lds[1] + lds[2] + lds[3];
}

__global__ __launch_bounds__(256) void lstm_loss_fin(
    const float* __restrict__ partials, float* __restrict__ out)
{
  __shared__ float lds[4];
  int tid = threadIdx.x;
  float s = partials[tid];
#pragma unroll
  for (int off = 32; off > 0; off >>= 1) s += __shfl_down(s, off, 64);
  if ((tid & 63) == 0) lds[tid >> 6] = s;
  __syncthreads();
  if (tid == 0) out[0] = (lds[0] + lds[1] + lds[2] + lds[3]) * (1.0f / 262144.0f);
}

extern "C" void kernel_launch(void* const* d_in, const int* in_sizes, int n_in,
                              void* d_out, int out_size, void* d_ws, size_t ws_size,
                              hipStream_t stream) {
  const float* x   = (const float*)d_in[0];
  const float* tgt = (const float*)d_in[1];
  const float* Wih = (const float*)d_in[2];
  const float* Whh = (const float*)d_in[3];

  float* out   = (float*)d_out;
  float* h_out = out + 1;                 // [256*1024]
  float* c_io  = out + 1 + BB * EE;       // [256*1024]

  // ws: xbf (16.8MB) | hroll 32 slots (16.8MB) | partials (1KB) | flags (64KB)
  short* xbf      = (short*)d_ws;
  short* hroll    = (short*)((char*)xbf + (size_t)LL * BB * EE * 2);
  float* partials = (float*)((char*)hroll + (size_t)LL * BB * EE * 2);
  unsigned* flags = (unsigned*)((char*)partials + 1024);

  lstm_prep<<<4096, 256, 0, stream>>>(x, xbf, c_io, flags);

  {
    const short* xbfA = xbf; const float* WihA = Wih; const float* WhhA = Whh;
    short* hrollA = hroll; float* cA = c_io; float* hA = h_out; unsigned* flagsA = flags;
    void* args[] = {&xbfA, &WihA, &WhhA, &hrollA, &cA, &hA, &flagsA};
    hipLaunchCooperativeKernel((void*)lstm_rec, dim3(256), dim3(512), args, 0, stream);
  }

  lstm_loss_part<<<256, 256, 0, stream>>>(h_out, tgt, partials);
  lstm_loss_fin<<<1, 256, 0, stream>>>(partials, out);
}